// Round 1
// baseline (1788.486 us; speedup 1.0000x reference)
//
#include <hip/hip_runtime.h>
#include <hip/hip_bf16.h>

// Problem constants
constexpr int Nb   = 16;
constexpr int Mdim = 2048;
constexpr int FINC = 16;
constexpr int KORD = 6;
constexpr int FOUTC = 128;

// Cheb pass tiling
constexpr int ROWS  = 64;               // rows per block
constexpr int NWIN  = 4;                // k-windows (one per wave)
constexpr int WINK  = Mdim / NWIN;      // 512
constexpr int CHUNK = 64;               // k per staging step
constexpr int LPAD  = 4;                // bf16 pad per LDS row

__device__ __forceinline__ float bf2f(unsigned short u) {
  return __uint_as_float(((unsigned int)u) << 16);
}
__device__ __forceinline__ unsigned short f2b(float f) {
  unsigned int u = __float_as_uint(f);
  u += 0x7FFFu + ((u >> 16) & 1u);      // round-to-nearest-even
  return (unsigned short)(u >> 16);
}

struct ChebSmem {
  union {
    unsigned short L[NWIN][ROWS][CHUNK + LPAD];  // 34816 B
    float partial[NWIN][ROWS][FINC];             // 16384 B (post-loop reuse)
  };
  float T[NWIN][CHUNK][FINC];                    // 16384 B
};

// One Chebyshev matmul pass: Y = L * Tprev ; Tout = FIRST ? Y : 2Y - Tprev2
// L source is f32 (F32SRC, converted to bf16 on the fly) or bf16 workspace.
template<bool F32SRC, bool WRITE_LB, bool FIRST>
__global__ __launch_bounds__(256)
void cheb_pass(const float* __restrict__ Lf,
               const unsigned short* __restrict__ Lb,
               unsigned short* __restrict__ LbOut,
               const float* __restrict__ Tprev,
               const float* __restrict__ Tprev2,
               float* __restrict__ Tout) {
  __shared__ ChebSmem sm;
  const int tid  = threadIdx.x;
  const int w    = tid >> 6;       // wave id -> k-window
  const int lane = tid & 63;       // lane -> row within block
  const int n       = blockIdx.x >> 5;
  const int rowbase = (blockIdx.x & 31) * ROWS;
  const size_t rowg0 = (size_t)n * Mdim + rowbase;

  float acc[FINC];
  #pragma unroll
  for (int f = 0; f < FINC; ++f) acc[f] = 0.f;

  for (int i = 0; i < WINK / CHUNK; ++i) {
    if (i) __syncthreads();

    // ---- stage T chunk for each window (256 float4 units per window) ----
    #pragma unroll
    for (int v = 0; v < NWIN; ++v) {
      const int kg = v * WINK + i * CHUNK;
      const int k  = tid >> 2, f4 = tid & 3;
      float4 tv = *reinterpret_cast<const float4*>(
          &Tprev[((size_t)n * Mdim + kg + k) * FINC + f4 * 4]);
      *reinterpret_cast<float4*>(&sm.T[v][k][f4 * 4]) = tv;
    }

    // ---- stage L chunk for each window (coalesced) ----
    #pragma unroll
    for (int v = 0; v < NWIN; ++v) {
      const int kg = v * WINK + i * CHUNK;
      #pragma unroll
      for (int j = 0; j < 4; ++j) {
        const int u  = tid + j * 256;     // 1024 units = 64 rows x 16
        const int r  = u >> 4, k4 = u & 15;
        const size_t gidx = (rowg0 + r) * (size_t)Mdim + kg + k4 * 4;
        ushort4 b;
        if (F32SRC) {
          float4 lv = *reinterpret_cast<const float4*>(&Lf[gidx]);
          b.x = f2b(lv.x); b.y = f2b(lv.y); b.z = f2b(lv.z); b.w = f2b(lv.w);
          if (WRITE_LB)
            *reinterpret_cast<ushort4*>(&LbOut[gidx]) = b;
        } else {
          b = *reinterpret_cast<const ushort4*>(&Lb[gidx]);
        }
        *reinterpret_cast<ushort4*>(&sm.L[v][r][k4 * 4]) = b;
      }
    }
    __syncthreads();

    // ---- compute: lane owns one row; wave owns k-window w ----
    #pragma unroll
    for (int k = 0; k < CHUNK; k += 4) {
      ushort4 l4 = *reinterpret_cast<const ushort4*>(&sm.L[w][lane][k]);
      unsigned short ls[4] = {l4.x, l4.y, l4.z, l4.w};
      #pragma unroll
      for (int j = 0; j < 4; ++j) {
        const float lf = bf2f(ls[j]);
        #pragma unroll
        for (int f = 0; f < FINC; f += 4) {
          // wave-uniform address -> LDS broadcast, conflict-free
          float4 tv = *reinterpret_cast<const float4*>(&sm.T[w][k + j][f]);
          acc[f]     = fmaf(lf, tv.x, acc[f]);
          acc[f + 1] = fmaf(lf, tv.y, acc[f + 1]);
          acc[f + 2] = fmaf(lf, tv.z, acc[f + 2]);
          acc[f + 3] = fmaf(lf, tv.w, acc[f + 3]);
        }
      }
    }
  }

  // ---- reduce partial sums across the 4 k-windows ----
  __syncthreads();
  #pragma unroll
  for (int f = 0; f < FINC; ++f) sm.partial[w][lane][f] = acc[f];
  __syncthreads();
  for (int o = tid; o < ROWS * FINC; o += 256) {
    const int r = o >> 4, f = o & 15;
    const float s = sm.partial[0][r][f] + sm.partial[1][r][f]
                  + sm.partial[2][r][f] + sm.partial[3][r][f];
    const size_t oi = (rowg0 + r) * FINC + f;
    const float val = FIRST ? s : 2.f * s - Tprev2[oi];
    Tout[oi] = val;
  }
}

// Epilogue: out = relu(feat @ W + B), feat[n*m][f*6+kk] = T_kk[n][m][f]
constexpr int EROWS = 32;
struct EpiSmem {
  float W[KORD * FINC][FOUTC];          // 49152 B
  float feat[EROWS][KORD * FINC + 1];   // 12416 B (pad -> bank = row+fi)
  float B[FOUTC];                       // 512 B
};

__global__ __launch_bounds__(256)
void epilogue_kernel(const float* __restrict__ x,
                     const float* __restrict__ Tws,   // T1 base, stride TSZ
                     const float* __restrict__ Wg,
                     const float* __restrict__ Bg,
                     float* __restrict__ out) {
  __shared__ EpiSmem sm;
  const int tid = threadIdx.x;
  const int n       = blockIdx.x >> 6;
  const int rowbase = (blockIdx.x & 63) * EROWS;
  constexpr size_t TSZ = (size_t)Nb * Mdim * FINC;

  for (int u = tid; u < (KORD * FINC * FOUTC) / 4; u += 256) {
    const int fi = u >> 5, fo4 = u & 31;
    *reinterpret_cast<float4*>(&sm.W[fi][fo4 * 4]) =
        *reinterpret_cast<const float4*>(&Wg[fi * FOUTC + fo4 * 4]);
  }
  if (tid < FOUTC / 4) {
    *reinterpret_cast<float4*>(&sm.B[tid * 4]) =
        *reinterpret_cast<const float4*>(&Bg[tid * 4]);
  }
  #pragma unroll
  for (int kk = 0; kk < KORD; ++kk) {
    const float* src = (kk == 0) ? x : (Tws + (size_t)(kk - 1) * TSZ);
    for (int u = tid; u < EROWS * FINC; u += 256) {
      const int r = u >> 4, f = u & 15;
      sm.feat[r][f * KORD + kk] =
          src[((size_t)n * Mdim + rowbase + r) * FINC + f];
    }
  }
  __syncthreads();

  const int row = tid & 31;
  const int fo8 = tid >> 5;
  float acc[16];
  #pragma unroll
  for (int q = 0; q < 16; ++q) acc[q] = sm.B[fo8 * 16 + q];

  #pragma unroll 4
  for (int fi = 0; fi < KORD * FINC; ++fi) {
    const float fv = sm.feat[row][fi];
    #pragma unroll
    for (int q = 0; q < 4; ++q) {
      float4 wv = *reinterpret_cast<const float4*>(&sm.W[fi][fo8 * 16 + q * 4]);
      acc[q * 4]     = fmaf(fv, wv.x, acc[q * 4]);
      acc[q * 4 + 1] = fmaf(fv, wv.y, acc[q * 4 + 1]);
      acc[q * 4 + 2] = fmaf(fv, wv.z, acc[q * 4 + 2]);
      acc[q * 4 + 3] = fmaf(fv, wv.w, acc[q * 4 + 3]);
    }
  }

  const size_t obase = ((size_t)n * Mdim + rowbase + row) * FOUTC + fo8 * 16;
  #pragma unroll
  for (int q = 0; q < 4; ++q) {
    float4 ov;
    ov.x = fmaxf(acc[q * 4], 0.f);
    ov.y = fmaxf(acc[q * 4 + 1], 0.f);
    ov.z = fmaxf(acc[q * 4 + 2], 0.f);
    ov.w = fmaxf(acc[q * 4 + 3], 0.f);
    *reinterpret_cast<float4*>(&out[obase + q * 4]) = ov;
  }
}

extern "C" void kernel_launch(void* const* d_in, const int* in_sizes, int n_in,
                              void* d_out, int out_size, void* d_ws, size_t ws_size,
                              hipStream_t stream) {
  const float* x = (const float*)d_in[0];
  const float* L = (const float*)d_in[1];
  const float* W = (const float*)d_in[2];
  const float* B = (const float*)d_in[3];
  float* out = (float*)d_out;

  const size_t LB_BYTES = (size_t)Nb * Mdim * Mdim * 2;   // bf16 L: 134 MB
  const size_t TSZ      = (size_t)Nb * Mdim * FINC;       // elems per T
  const size_t T_BYTES  = TSZ * 4 * 5;                    // T1..T5: 10.5 MB
  const bool lb = ws_size >= LB_BYTES + T_BYTES;

  char* ws = (char*)d_ws;
  unsigned short* Lb = (unsigned short*)ws;
  float* T1 = (float*)(ws + (lb ? LB_BYTES : 0));
  float* T2 = T1 + TSZ;
  float* T3 = T2 + TSZ;
  float* T4 = T3 + TSZ;
  float* T5 = T4 + TSZ;

  dim3 grid(Nb * (Mdim / ROWS));   // 512
  dim3 blk(256);

  if (lb) {
    // pass 1: read f32 L, emit bf16 L, T1 = L x
    hipLaunchKernelGGL((cheb_pass<true, true, true>), grid, blk, 0, stream,
                       L, nullptr, Lb, x, nullptr, T1);
    hipLaunchKernelGGL((cheb_pass<false, false, false>), grid, blk, 0, stream,
                       nullptr, Lb, nullptr, T1, x, T2);
    hipLaunchKernelGGL((cheb_pass<false, false, false>), grid, blk, 0, stream,
                       nullptr, Lb, nullptr, T2, T1, T3);
    hipLaunchKernelGGL((cheb_pass<false, false, false>), grid, blk, 0, stream,
                       nullptr, Lb, nullptr, T3, T2, T4);
    hipLaunchKernelGGL((cheb_pass<false, false, false>), grid, blk, 0, stream,
                       nullptr, Lb, nullptr, T4, T3, T5);
  } else {
    // workspace too small for bf16 L copy: stream f32 L every pass
    hipLaunchKernelGGL((cheb_pass<true, false, true>), grid, blk, 0, stream,
                       L, nullptr, nullptr, x, nullptr, T1);
    hipLaunchKernelGGL((cheb_pass<true, false, false>), grid, blk, 0, stream,
                       L, nullptr, nullptr, T1, x, T2);
    hipLaunchKernelGGL((cheb_pass<true, false, false>), grid, blk, 0, stream,
                       L, nullptr, nullptr, T2, T1, T3);
    hipLaunchKernelGGL((cheb_pass<true, false, false>), grid, blk, 0, stream,
                       L, nullptr, nullptr, T3, T2, T4);
    hipLaunchKernelGGL((cheb_pass<true, false, false>), grid, blk, 0, stream,
                       L, nullptr, nullptr, T4, T3, T5);
  }

  hipLaunchKernelGGL(epilogue_kernel, dim3(Nb * (Mdim / EROWS)), blk, 0, stream,
                     x, T1, W, B, out);
}

// Round 2
// 267.476 us; speedup vs baseline: 6.6865x; 6.6865x over previous
//
#include <hip/hip_runtime.h>
#include <hip/hip_bf16.h>

constexpr int Nb    = 16;
constexpr int Mdim  = 2048;
constexpr int FINC  = 16;
constexpr int KORD  = 6;
constexpr int FOUTC = 128;

typedef __attribute__((ext_vector_type(8))) short bf16x8;
typedef __attribute__((ext_vector_type(4))) float f32x4;

__device__ __forceinline__ unsigned short f2b(float f) {
  unsigned int u = __float_as_uint(f);
  u += 0x7FFFu + ((u >> 16) & 1u);      // round-to-nearest-even
  return (unsigned short)(u >> 16);
}

// Transpose x[n][m][f] f32 -> xt_f[n][f][m] f32 and xt_b[n][f][m] bf16.
// x is 2 MB total; the strided reads are L2-absorbed.
__global__ __launch_bounds__(256)
void prep_kernel(const float* __restrict__ x,
                 float* __restrict__ xt_f,
                 unsigned short* __restrict__ xt_b) {
  const int n = blockIdx.x >> 4, f = blockIdx.x & 15;
  for (int m = threadIdx.x; m < Mdim; m += 256) {
    const float v = x[((size_t)n * Mdim + m) * FINC + f];
    const size_t o = ((size_t)n * FINC + f) * Mdim + m;
    xt_f[o] = v;
    xt_b[o] = f2b(v);
  }
}

// One Chebyshev pass via MFMA, no LDS in the K-loop.
// Wave computes D[16f x 16rows] for rows [row0, row0+16):
//   A = Tprev^T (16 x K)  from At (bf16, [n][16][2048])
//   B = L rows  (K x 16)  from Lf (f32) or Lb (bf16), row-major [n][2048][2048]
// Output: Tf/Tb transposed [n][16][2048];  val = FIRST ? Y : 2Y - P2t.
template<bool F32SRC, bool WRITE_LB, bool FIRST>
__global__ __launch_bounds__(256)
void cheb_mfma(const float* __restrict__ Lf,
               const unsigned short* __restrict__ Lb,
               unsigned short* __restrict__ LbOut,
               const unsigned short* __restrict__ At,
               const float* __restrict__ P2t,
               float* __restrict__ Tf,
               unsigned short* __restrict__ Tb) {
  const int tid  = threadIdx.x;
  const int wave = tid >> 6;
  const int lane = tid & 63;
  const int n    = blockIdx.x >> 5;                       // 32 blocks per n
  const int row0 = (blockIdx.x & 31) * 64 + wave * 16;    // 16-row tile
  const int lr   = lane & 15;    // D col = L-row offset; also A row (f) for loads
  const int g    = lane >> 4;    // k-group

  const size_t Lrow  = ((size_t)n * Mdim + row0 + lr) * Mdim;
  const size_t Abase = ((size_t)n * FINC + lr) * Mdim;

  f32x4 acc = {0.f, 0.f, 0.f, 0.f};

  #pragma unroll 4
  for (int k0 = 0; k0 < Mdim; k0 += 32) {
    const int ka = k0 + g * 8;

    // A fragment: Tprev^T[f=lr][ka..ka+8)  (16 B/lane, L1/L2-hot)
    bf16x8 a = *reinterpret_cast<const bf16x8*>(At + Abase + ka);

    // B fragment: L[row0+lr][ka..ka+8)  (16 B/lane, streams L once)
    bf16x8 b;
    if (F32SRC) {
      f32x4 lo = *reinterpret_cast<const f32x4*>(Lf + Lrow + ka);
      f32x4 hi = *reinterpret_cast<const f32x4*>(Lf + Lrow + ka + 4);
      b[0] = (short)f2b(lo.x); b[1] = (short)f2b(lo.y);
      b[2] = (short)f2b(lo.z); b[3] = (short)f2b(lo.w);
      b[4] = (short)f2b(hi.x); b[5] = (short)f2b(hi.y);
      b[6] = (short)f2b(hi.z); b[7] = (short)f2b(hi.w);
      if (WRITE_LB)
        *reinterpret_cast<bf16x8*>(LbOut + Lrow + ka) = b;
    } else {
      b = *reinterpret_cast<const bf16x8*>(Lb + Lrow + ka);
    }

    acc = __builtin_amdgcn_mfma_f32_16x16x32_bf16(a, b, acc, 0, 0, 0);
  }

  // D layout (m89-verified): col = lane&15, row = (lane>>4)*4 + r.
  // Here m (D row) = f, n (D col) = L-row offset.
  #pragma unroll
  for (int r = 0; r < 4; ++r) {
    const int f = g * 4 + r;
    const size_t o = ((size_t)n * FINC + f) * Mdim + row0 + lr;
    const float v = FIRST ? acc[r] : 2.f * acc[r] - P2t[o];
    Tf[o] = v;
    Tb[o] = f2b(v);
  }
}

// Epilogue: out = relu(feat @ W + B); feat[n*m][f*6+kk] = T_kk^T[n][f][m]
constexpr int EROWS = 32;
struct EpiSmem {
  float W[KORD * FINC][FOUTC];          // 49152 B
  float feat[EROWS][KORD * FINC + 1];   // 12416 B
  float B[FOUTC];                       // 512 B
};

__global__ __launch_bounds__(256)
void epilogue_kernel(const float* __restrict__ xt,     // [n][16][2048] f32
                     const float* __restrict__ Tws,    // T1..T5, stride TSZ
                     const float* __restrict__ Wg,
                     const float* __restrict__ Bg,
                     float* __restrict__ out) {
  __shared__ EpiSmem sm;
  const int tid = threadIdx.x;
  const int n       = blockIdx.x >> 6;
  const int rowbase = (blockIdx.x & 63) * EROWS;
  constexpr size_t TSZ = (size_t)Nb * Mdim * FINC;

  for (int u = tid; u < (KORD * FINC * FOUTC) / 4; u += 256) {
    const int fi = u >> 5, fo4 = u & 31;
    *reinterpret_cast<float4*>(&sm.W[fi][fo4 * 4]) =
        *reinterpret_cast<const float4*>(&Wg[fi * FOUTC + fo4 * 4]);
  }
  if (tid < FOUTC / 4) {
    *reinterpret_cast<float4*>(&sm.B[tid * 4]) =
        *reinterpret_cast<const float4*>(&Bg[tid * 4]);
  }
  #pragma unroll
  for (int kk = 0; kk < KORD; ++kk) {
    const float* src = (kk == 0) ? xt : (Tws + (size_t)(kk - 1) * TSZ);
    for (int u = tid; u < EROWS * FINC; u += 256) {
      const int r = u & 31, f = u >> 5;     // r consecutive -> coalesced
      sm.feat[r][f * KORD + kk] =
          src[((size_t)n * FINC + f) * Mdim + rowbase + r];
    }
  }
  __syncthreads();

  const int row = tid & 31;
  const int fo8 = tid >> 5;
  float acc[16];
  #pragma unroll
  for (int q = 0; q < 16; ++q) acc[q] = sm.B[fo8 * 16 + q];

  #pragma unroll 4
  for (int fi = 0; fi < KORD * FINC; ++fi) {
    const float fv = sm.feat[row][fi];
    #pragma unroll
    for (int q = 0; q < 4; ++q) {
      float4 wv = *reinterpret_cast<const float4*>(&sm.W[fi][fo8 * 16 + q * 4]);
      acc[q * 4]     = fmaf(fv, wv.x, acc[q * 4]);
      acc[q * 4 + 1] = fmaf(fv, wv.y, acc[q * 4 + 1]);
      acc[q * 4 + 2] = fmaf(fv, wv.z, acc[q * 4 + 2]);
      acc[q * 4 + 3] = fmaf(fv, wv.w, acc[q * 4 + 3]);
    }
  }

  const size_t obase = ((size_t)n * Mdim + rowbase + row) * FOUTC + fo8 * 16;
  #pragma unroll
  for (int q = 0; q < 4; ++q) {
    float4 ov;
    ov.x = fmaxf(acc[q * 4], 0.f);
    ov.y = fmaxf(acc[q * 4 + 1], 0.f);
    ov.z = fmaxf(acc[q * 4 + 2], 0.f);
    ov.w = fmaxf(acc[q * 4 + 3], 0.f);
    *reinterpret_cast<float4*>(&out[obase + q * 4]) = ov;
  }
}

extern "C" void kernel_launch(void* const* d_in, const int* in_sizes, int n_in,
                              void* d_out, int out_size, void* d_ws, size_t ws_size,
                              hipStream_t stream) {
  const float* x = (const float*)d_in[0];
  const float* L = (const float*)d_in[1];
  const float* W = (const float*)d_in[2];
  const float* B = (const float*)d_in[3];
  float* out = (float*)d_out;

  constexpr size_t TSZ      = (size_t)Nb * Mdim * FINC;     // 524288 elems
  constexpr size_t LB_ELEMS = (size_t)Nb * Mdim * Mdim;
  const size_t need_full = LB_ELEMS * 2 + TSZ * 4 * 6 + TSZ * 2 * 6;  // ~152 MB
  const bool lb = ws_size >= need_full;

  char* p = (char*)d_ws;
  unsigned short* Lbuf = (unsigned short*)p;
  if (lb) p += LB_ELEMS * 2;
  float* xt_f = (float*)p;            p += TSZ * 4;
  float* T1f  = (float*)p;            p += TSZ * 4 * 5;
  unsigned short* xt_b = (unsigned short*)p;  p += TSZ * 2;
  unsigned short* T1b  = (unsigned short*)p;

  float*          Tf[5] = {T1f, T1f + TSZ, T1f + 2 * TSZ, T1f + 3 * TSZ, T1f + 4 * TSZ};
  unsigned short* Tb[5] = {T1b, T1b + TSZ, T1b + 2 * TSZ, T1b + 3 * TSZ, T1b + 4 * TSZ};

  dim3 blk(256);
  hipLaunchKernelGGL(prep_kernel, dim3(Nb * FINC), blk, 0, stream, x, xt_f, xt_b);

  dim3 grid(Nb * 32);   // 512 blocks, 4 waves each, one 16-row tile per wave
  if (lb) {
    hipLaunchKernelGGL((cheb_mfma<true, true, true>), grid, blk, 0, stream,
                       L, nullptr, Lbuf, xt_b, nullptr, Tf[0], Tb[0]);
    hipLaunchKernelGGL((cheb_mfma<false, false, false>), grid, blk, 0, stream,
                       nullptr, Lbuf, nullptr, Tb[0], xt_f, Tf[1], Tb[1]);
    hipLaunchKernelGGL((cheb_mfma<false, false, false>), grid, blk, 0, stream,
                       nullptr, Lbuf, nullptr, Tb[1], Tf[0], Tf[2], Tb[2]);
    hipLaunchKernelGGL((cheb_mfma<false, false, false>), grid, blk, 0, stream,
                       nullptr, Lbuf, nullptr, Tb[2], Tf[1], Tf[3], Tb[3]);
    hipLaunchKernelGGL((cheb_mfma<false, false, false>), grid, blk, 0, stream,
                       nullptr, Lbuf, nullptr, Tb[3], Tf[2], Tf[4], Tb[4]);
  } else {
    hipLaunchKernelGGL((cheb_mfma<true, false, true>), grid, blk, 0, stream,
                       L, nullptr, nullptr, xt_b, nullptr, Tf[0], Tb[0]);
    hipLaunchKernelGGL((cheb_mfma<true, false, false>), grid, blk, 0, stream,
                       L, nullptr, nullptr, Tb[0], xt_f, Tf[1], Tb[1]);
    hipLaunchKernelGGL((cheb_mfma<true, false, false>), grid, blk, 0, stream,
                       L, nullptr, nullptr, Tb[1], Tf[0], Tf[2], Tb[2]);
    hipLaunchKernelGGL((cheb_mfma<true, false, false>), grid, blk, 0, stream,
                       L, nullptr, nullptr, Tb[2], Tf[1], Tf[3], Tb[3]);
    hipLaunchKernelGGL((cheb_mfma<true, false, false>), grid, blk, 0, stream,
                       L, nullptr, nullptr, Tb[3], Tf[2], Tf[4], Tb[4]);
  }

  hipLaunchKernelGGL(epilogue_kernel, dim3(Nb * (Mdim / EROWS)), blk, 0, stream,
                     xt_f, T1f, W, B, out);
}

// Round 3
// 259.565 us; speedup vs baseline: 6.8903x; 1.0305x over previous
//
#include <hip/hip_runtime.h>
#include <hip/hip_bf16.h>

constexpr int Nb    = 16;
constexpr int Mdim  = 2048;
constexpr int FINC  = 16;
constexpr int KORD  = 6;
constexpr int FOUTC = 128;

typedef __attribute__((ext_vector_type(8))) short bf16x8;
typedef __attribute__((ext_vector_type(4))) float f32x4;

__device__ __forceinline__ unsigned short f2b(float f) {
  unsigned int u = __float_as_uint(f);
  u += 0x7FFFu + ((u >> 16) & 1u);      // round-to-nearest-even
  return (unsigned short)(u >> 16);
}

// Transpose x[n][m][f] f32 -> xt_f[n][f][m] f32 and xt_b[n][f][m] bf16.
__global__ __launch_bounds__(256)
void prep_kernel(const float* __restrict__ x,
                 float* __restrict__ xt_f,
                 unsigned short* __restrict__ xt_b) {
  const int n = blockIdx.x >> 4, f = blockIdx.x & 15;
  for (int m = threadIdx.x; m < Mdim; m += 256) {
    const float v = x[((size_t)n * Mdim + m) * FINC + f];
    const size_t o = ((size_t)n * FINC + f) * Mdim + m;
    xt_f[o] = v;
    xt_b[o] = f2b(v);
  }
}

// One Chebyshev pass via MFMA, no LDS in the K-loop.
// 2-way K-split: tile (16 rows) handled by 2 waves, kh=0 -> k[0,1024),
// kh=1 -> k[1024,2048); partials combined through LDS.
//   A = Tprev^T (16 x K) from At (bf16, [n][16][2048])
//   B = L rows  (K x 16) from Lf (f32) or Lb (bf16)
// Output transposed: Tf/Tb [n][16][2048]; val = FIRST ? Y : 2Y - P2t.
template<bool F32SRC, bool WRITE_LB, bool FIRST>
__global__ __launch_bounds__(256, 4)
void cheb_mfma(const float* __restrict__ Lf,
               const unsigned short* __restrict__ Lb,
               unsigned short* __restrict__ LbOut,
               const unsigned short* __restrict__ At,
               const float* __restrict__ P2t,
               float* __restrict__ Tf,
               unsigned short* __restrict__ Tb) {
  constexpr int UNR = F32SRC ? 4 : 8;
  const int tid  = threadIdx.x;
  const int wave = tid >> 6;
  const int lane = tid & 63;
  const int tile = wave >> 1;          // 2 tiles per block
  const int kh   = wave & 1;           // k-half
  const int n    = blockIdx.x >> 6;                      // 64 blocks per n
  const int row0 = (blockIdx.x & 63) * 32 + tile * 16;   // 16-row tile
  const int lr   = lane & 15;   // D col = L-row offset; A row (f) for loads
  const int g    = lane >> 4;   // k-group

  const size_t Lrow  = ((size_t)n * Mdim + row0 + lr) * Mdim;
  const size_t Abase = ((size_t)n * FINC + lr) * Mdim;
  const int kbase = kh * (Mdim / 2);

  f32x4 acc = {0.f, 0.f, 0.f, 0.f};

  for (int k0 = kbase; k0 < kbase + Mdim / 2; k0 += 32 * UNR) {
    #pragma unroll
    for (int uu = 0; uu < UNR; ++uu) {
      const int ka = k0 + uu * 32 + g * 8;

      // A fragment: Tprev^T[f=lr][ka..ka+8)  (L1/L2-hot: shared by all waves of n)
      bf16x8 a = *reinterpret_cast<const bf16x8*>(At + Abase + ka);

      // B fragment: L[row0+lr][ka..ka+8)  (streams L once; L3-resident for bf16)
      bf16x8 b;
      if (F32SRC) {
        f32x4 lo = *reinterpret_cast<const f32x4*>(Lf + Lrow + ka);
        f32x4 hi = *reinterpret_cast<const f32x4*>(Lf + Lrow + ka + 4);
        b[0] = (short)f2b(lo.x); b[1] = (short)f2b(lo.y);
        b[2] = (short)f2b(lo.z); b[3] = (short)f2b(lo.w);
        b[4] = (short)f2b(hi.x); b[5] = (short)f2b(hi.y);
        b[6] = (short)f2b(hi.z); b[7] = (short)f2b(hi.w);
        if (WRITE_LB)
          *reinterpret_cast<bf16x8*>(LbOut + Lrow + ka) = b;
      } else {
        b = *reinterpret_cast<const bf16x8*>(Lb + Lrow + ka);
      }

      acc = __builtin_amdgcn_mfma_f32_16x16x32_bf16(a, b, acc, 0, 0, 0);
    }
  }

  // combine the two k-halves
  __shared__ f32x4 part[2][64];
  if (kh == 1) part[tile][lane] = acc;
  __syncthreads();
  if (kh == 0) {
    const f32x4 o = part[tile][lane];
    // D layout (m89-verified): col = lane&15, row = (lane>>4)*4 + r.
    #pragma unroll
    for (int r = 0; r < 4; ++r) {
      const int f = g * 4 + r;
      const size_t oi = ((size_t)n * FINC + f) * Mdim + row0 + lr;
      float v = acc[r] + o[r];
      v = FIRST ? v : 2.f * v - P2t[oi];
      Tf[oi] = v;
      Tb[oi] = f2b(v);
    }
  }
}

// Epilogue: out = relu(feat @ W + B); feat[n*m][f*6+kk] = T_kk^T[n][f][m]
constexpr int EROWS = 32;
struct EpiSmem {
  float W[KORD * FINC][FOUTC];          // 49152 B
  float feat[EROWS][KORD * FINC + 1];   // 12416 B
  float B[FOUTC];                       // 512 B
};

__global__ __launch_bounds__(256)
void epilogue_kernel(const float* __restrict__ xt,     // [n][16][2048] f32
                     const float* __restrict__ Tws,    // T1..T5, stride TSZ
                     const float* __restrict__ Wg,
                     const float* __restrict__ Bg,
                     float* __restrict__ out) {
  __shared__ EpiSmem sm;
  const int tid = threadIdx.x;
  const int n       = blockIdx.x >> 6;
  const int rowbase = (blockIdx.x & 63) * EROWS;
  constexpr size_t TSZ = (size_t)Nb * Mdim * FINC;

  for (int u = tid; u < (KORD * FINC * FOUTC) / 4; u += 256) {
    const int fi = u >> 5, fo4 = u & 31;
    *reinterpret_cast<float4*>(&sm.W[fi][fo4 * 4]) =
        *reinterpret_cast<const float4*>(&Wg[fi * FOUTC + fo4 * 4]);
  }
  if (tid < FOUTC / 4) {
    *reinterpret_cast<float4*>(&sm.B[tid * 4]) =
        *reinterpret_cast<const float4*>(&Bg[tid * 4]);
  }
  #pragma unroll
  for (int kk = 0; kk < KORD; ++kk) {
    const float* src = (kk == 0) ? xt : (Tws + (size_t)(kk - 1) * TSZ);
    for (int u = tid; u < EROWS * FINC; u += 256) {
      const int r = u & 31, f = u >> 5;     // r consecutive -> coalesced
      sm.feat[r][f * KORD + kk] =
          src[((size_t)n * FINC + f) * Mdim + rowbase + r];
    }
  }
  __syncthreads();

  const int row = tid & 31;
  const int fo8 = tid >> 5;
  float acc[16];
  #pragma unroll
  for (int q = 0; q < 16; ++q) acc[q] = sm.B[fo8 * 16 + q];

  #pragma unroll 4
  for (int fi = 0; fi < KORD * FINC; ++fi) {
    const float fv = sm.feat[row][fi];
    #pragma unroll
    for (int q = 0; q < 4; ++q) {
      float4 wv = *reinterpret_cast<const float4*>(&sm.W[fi][fo8 * 16 + q * 4]);
      acc[q * 4]     = fmaf(fv, wv.x, acc[q * 4]);
      acc[q * 4 + 1] = fmaf(fv, wv.y, acc[q * 4 + 1]);
      acc[q * 4 + 2] = fmaf(fv, wv.z, acc[q * 4 + 2]);
      acc[q * 4 + 3] = fmaf(fv, wv.w, acc[q * 4 + 3]);
    }
  }

  const size_t obase = ((size_t)n * Mdim + rowbase + row) * FOUTC + fo8 * 16;
  #pragma unroll
  for (int q = 0; q < 4; ++q) {
    float4 ov;
    ov.x = fmaxf(acc[q * 4], 0.f);
    ov.y = fmaxf(acc[q * 4 + 1], 0.f);
    ov.z = fmaxf(acc[q * 4 + 2], 0.f);
    ov.w = fmaxf(acc[q * 4 + 3], 0.f);
    *reinterpret_cast<float4*>(&out[obase + q * 4]) = ov;
  }
}

extern "C" void kernel_launch(void* const* d_in, const int* in_sizes, int n_in,
                              void* d_out, int out_size, void* d_ws, size_t ws_size,
                              hipStream_t stream) {
  const float* x = (const float*)d_in[0];
  const float* L = (const float*)d_in[1];
  const float* W = (const float*)d_in[2];
  const float* B = (const float*)d_in[3];
  float* out = (float*)d_out;

  constexpr size_t TSZ      = (size_t)Nb * Mdim * FINC;     // 524288 elems
  constexpr size_t LB_ELEMS = (size_t)Nb * Mdim * Mdim;
  const size_t need_full = LB_ELEMS * 2 + TSZ * 4 * 6 + TSZ * 2 * 6;  // ~152 MB
  const bool lb = ws_size >= need_full;

  char* p = (char*)d_ws;
  unsigned short* Lbuf = (unsigned short*)p;
  if (lb) p += LB_ELEMS * 2;
  float* xt_f = (float*)p;            p += TSZ * 4;
  float* T1f  = (float*)p;            p += TSZ * 4 * 5;
  unsigned short* xt_b = (unsigned short*)p;  p += TSZ * 2;
  unsigned short* T1b  = (unsigned short*)p;

  float*          Tf[5] = {T1f, T1f + TSZ, T1f + 2 * TSZ, T1f + 3 * TSZ, T1f + 4 * TSZ};
  unsigned short* Tb[5] = {T1b, T1b + TSZ, T1b + 2 * TSZ, T1b + 3 * TSZ, T1b + 4 * TSZ};

  dim3 blk(256);
  hipLaunchKernelGGL(prep_kernel, dim3(Nb * FINC), blk, 0, stream, x, xt_f, xt_b);

  dim3 grid(Nb * 64);   // 1024 blocks: 2 tiles/block x 2 k-half waves
  if (lb) {
    hipLaunchKernelGGL((cheb_mfma<true, true, true>), grid, blk, 0, stream,
                       L, nullptr, Lbuf, xt_b, nullptr, Tf[0], Tb[0]);
    hipLaunchKernelGGL((cheb_mfma<false, false, false>), grid, blk, 0, stream,
                       nullptr, Lbuf, nullptr, Tb[0], xt_f, Tf[1], Tb[1]);
    hipLaunchKernelGGL((cheb_mfma<false, false, false>), grid, blk, 0, stream,
                       nullptr, Lbuf, nullptr, Tb[1], Tf[0], Tf[2], Tb[2]);
    hipLaunchKernelGGL((cheb_mfma<false, false, false>), grid, blk, 0, stream,
                       nullptr, Lbuf, nullptr, Tb[2], Tf[1], Tf[3], Tb[3]);
    hipLaunchKernelGGL((cheb_mfma<false, false, false>), grid, blk, 0, stream,
                       nullptr, Lbuf, nullptr, Tb[3], Tf[2], Tf[4], Tb[4]);
  } else {
    hipLaunchKernelGGL((cheb_mfma<true, false, true>), grid, blk, 0, stream,
                       L, nullptr, nullptr, xt_b, nullptr, Tf[0], Tb[0]);
    hipLaunchKernelGGL((cheb_mfma<true, false, false>), grid, blk, 0, stream,
                       L, nullptr, nullptr, Tb[0], xt_f, Tf[1], Tb[1]);
    hipLaunchKernelGGL((cheb_mfma<true, false, false>), grid, blk, 0, stream,
                       L, nullptr, nullptr, Tb[1], Tf[0], Tf[2], Tb[2]);
    hipLaunchKernelGGL((cheb_mfma<true, false, false>), grid, blk, 0, stream,
                       L, nullptr, nullptr, Tb[2], Tf[1], Tf[3], Tb[3]);
    hipLaunchKernelGGL((cheb_mfma<true, false, false>), grid, blk, 0, stream,
                       L, nullptr, nullptr, Tb[3], Tf[2], Tf[4], Tb[4]);
  }

  hipLaunchKernelGGL(epilogue_kernel, dim3(Nb * (Mdim / EROWS)), blk, 0, stream,
                     xt_f, T1f, W, B, out);
}